// Round 8
// baseline (266.534 us; speedup 1.0000x reference)
//
#include <hip/hip_runtime.h>
#include <hip/hip_bf16.h>
#include <math.h>

#define Bsz 2
#define Tsz 2048
#define Csz 1024
#define Hsz 16
#define Dsz 64

typedef __attribute__((ext_vector_type(8))) short frag8;      // 8 bf16
typedef __attribute__((ext_vector_type(4))) float f4;         // MFMA C/D
typedef __attribute__((ext_vector_type(8))) unsigned short us8;
typedef __attribute__((ext_vector_type(4))) _Float16 frag4h;  // 4 f16
typedef __attribute__((ext_vector_type(8))) _Float16 frag8h;  // 8 f16

static __device__ __forceinline__ unsigned short f2bf(float f) {
  union { __hip_bfloat16 h; unsigned short u; } c;
  c.h = __float2bfloat16(f);
  return c.u;
}
static __device__ __forceinline__ unsigned short f2h(float f) {
  union { _Float16 h; unsigned short u; } c;
  c.h = (_Float16)f;
  return c.u;
}

#define GLDS16(g, l)                                                        \
  __builtin_amdgcn_global_load_lds(                                         \
      (const __attribute__((address_space(1))) void*)(g),                   \
      (__attribute__((address_space(3))) void*)(l), 16, 0, 0)

// Q pre-scale: 1/sqrt(64) * log2(e)  (exp2 in attention)
#define QSCALE 0.18033688f

// ---------------------------------------------------------------------------
// cast x fp32 -> bf16
// ---------------------------------------------------------------------------
__global__ __launch_bounds__(256) void cast_x(const float* __restrict__ x,
                                              unsigned short* __restrict__ xb) {
  const int i = (blockIdx.x * 256 + threadIdx.x) * 8;
  const float4 a = *(const float4*)(x + i);
  const float4 b = *(const float4*)(x + i + 4);
  us8 v;
  v[0] = f2bf(a.x); v[1] = f2bf(a.y); v[2] = f2bf(a.z); v[3] = f2bf(a.w);
  v[4] = f2bf(b.x); v[5] = f2bf(b.y); v[6] = f2bf(b.z); v[7] = f2bf(b.w);
  *(us8*)(xb + i) = v;
}

// ---------------------------------------------------------------------------
// Transpose-cast: 4x fp32 [1024][1024] -> bf16 transposed.
// ---------------------------------------------------------------------------
__global__ __launch_bounds__(256) void transpose_cast(
    const float* __restrict__ s0, const float* __restrict__ s1,
    const float* __restrict__ s2, const float* __restrict__ s3,
    unsigned short* __restrict__ d0, unsigned short* __restrict__ d1,
    unsigned short* __restrict__ d2, unsigned short* __restrict__ d3) {
  __shared__ float Ls[64][65];
  const int mat = blockIdx.x >> 8;
  const int tile = blockIdx.x & 255;
  const float* src = mat == 0 ? s0 : mat == 1 ? s1 : mat == 2 ? s2 : s3;
  unsigned short* dst = mat == 0 ? d0 : mat == 1 ? d1 : mat == 2 ? d2 : d3;
  const int tr0 = (tile >> 4) << 6, tc0 = (tile & 15) << 6;
  const int t = threadIdx.x;
  const int lr = t >> 4, lc = (t & 15) << 2;
#pragma unroll
  for (int j = 0; j < 4; ++j) {
    const float4 v = *(const float4*)(src + (size_t)(tr0 + lr + j * 16) * 1024 + tc0 + lc);
    Ls[lr + j * 16][lc + 0] = v.x;
    Ls[lr + j * 16][lc + 1] = v.y;
    Ls[lr + j * 16][lc + 2] = v.z;
    Ls[lr + j * 16][lc + 3] = v.w;
  }
  __syncthreads();
#pragma unroll
  for (int j = 0; j < 4; ++j) {
    ushort4 v;
    v.x = f2bf(Ls[lc + 0][lr + j * 16]);
    v.y = f2bf(Ls[lc + 1][lr + j * 16]);
    v.z = f2bf(Ls[lc + 2][lr + j * 16]);
    v.w = f2bf(Ls[lc + 3][lr + j * 16]);
    *(ushort4*)(dst + (size_t)(tc0 + lr + j * 16) * 1024 + tr0 + lc) = v;
  }
}

// ---------------------------------------------------------------------------
// bf16 MFMA GEMM: C[M][N] = A[M][K=1024] . Bt[N][K]^T.  BK=64, 128-col tile.
// MODE 0 (MT=4): fused QKV (N=3072): col<1024 -> Qb (*QSCALE) bf16 [B,H,T,D];
//     col<2048 -> Kb bf16 [B,H,T,D]; else -> VTb f16 [B,H,D,T'] key-swizzled.
// MODE 2 (MT=2): OUT: fp32 + bias, [M][1024]
// ---------------------------------------------------------------------------
template <int MODE, int MT>
__global__ __launch_bounds__(256) void mm_bt(
    const unsigned short* __restrict__ A, const unsigned short* __restrict__ Bt,
    const float* __restrict__ bias, unsigned short* __restrict__ O0,
    unsigned short* __restrict__ O1, unsigned short* __restrict__ O2,
    float* __restrict__ Of) {
  __shared__ __align__(16) unsigned short As[MT * 32 * 64];
  __shared__ __align__(16) unsigned short Bs[128 * 64];
  const int K = 1024;
  const int tid = threadIdx.x;
  const int wave = tid >> 6, lane = tid & 63;
  const int quad = lane >> 4, l16 = lane & 15;
  const int wrow = (wave >> 1) * (MT * 16), wn = wave & 1;
  const int row0 = blockIdx.y * (MT * 32), col0 = blockIdx.x << 7;

  const int sr = lane >> 3, sg = lane & 7;
  const int g0 = sg ^ sr;
  const unsigned short* gA = A + (size_t)(row0 + wave * (MT * 8) + sr) * K + (g0 << 3);
  const unsigned short* gB = Bt + (size_t)(col0 + wave * 32 + sr) * K + (g0 << 3);

  f4 acc[MT][4];
#pragma unroll
  for (int i = 0; i < MT; ++i)
#pragma unroll
    for (int j = 0; j < 4; ++j) acc[i][j] = (f4){0.f, 0.f, 0.f, 0.f};

  for (int kk = 0; kk < K; kk += 64) {
    __syncthreads();
#pragma unroll
    for (int s = 0; s < MT; ++s)
      GLDS16(gA + kk + (size_t)(s * 8) * K, &As[(wave * (MT * 8) + s * 8) * 64]);
#pragma unroll
    for (int s = 0; s < 4; ++s)
      GLDS16(gB + kk + (size_t)(s * 8) * K, &Bs[(wave * 32 + s * 8) * 64]);
    __syncthreads();

#pragma unroll
    for (int ks = 0; ks < 2; ++ks) {
      frag8 af[MT], bf[4];
#pragma unroll
      for (int mt = 0; mt < MT; ++mt) {
        const int r = wrow + mt * 16 + l16;
        af[mt] = *(const frag8*)&As[r * 64 + (((ks * 4 + quad) ^ (l16 & 7)) << 3)];
      }
#pragma unroll
      for (int nt = 0; nt < 4; ++nt) {
        const int n = wn * 64 + nt * 16 + l16;
        bf[nt] = *(const frag8*)&Bs[n * 64 + (((ks * 4 + quad) ^ (l16 & 7)) << 3)];
      }
#pragma unroll
      for (int mt = 0; mt < MT; ++mt)
#pragma unroll
        for (int nt = 0; nt < 4; ++nt)
          acc[mt][nt] = __builtin_amdgcn_mfma_f32_16x16x32_bf16(af[mt], bf[nt], acc[mt][nt], 0, 0, 0);
    }
  }

  // ---- epilogue. C/D: col = l16, row = quad*4 + reg.
  if (MODE == 0) {
    if (col0 < 2048) {
      const bool isK = (col0 >= 1024);
      unsigned short* dst = isK ? O1 : O0;
      const float sc = isK ? 1.0f : QSCALE;
#pragma unroll
      for (int mt = 0; mt < MT; ++mt)
#pragma unroll
        for (int nt = 0; nt < 4; ++nt) {
          const int m = row0 + wrow + mt * 16 + quad * 4;          // token
          const int n = (col0 & 1023) + wn * 64 + nt * 16 + l16;   // channel
          const int b = m >> 11, h = n >> 6, d = n & 63;
#pragma unroll
          for (int r = 0; r < 4; ++r) {
            const int tk = (m + r) & (Tsz - 1);
            dst[(((size_t)b * Hsz + h) * Tsz + tk) * Dsz + d] = f2bf(acc[mt][nt][r] * sc);
          }
        }
    } else {
      // V^T f16 [B,H,D,T'] key-swizzled; 4 consecutive tokens packed
#pragma unroll
      for (int mt = 0; mt < MT; ++mt)
#pragma unroll
        for (int nt = 0; nt < 4; ++nt) {
          const int tok = row0 + wrow + mt * 16 + quad * 4;
          const int ch = (col0 - 2048) + wn * 64 + nt * 16 + l16;
          const int b = tok >> 11, tk = tok & (Tsz - 1);
          const int h = ch >> 6, d = ch & 63;
          const int t5 = tk & 31;
          const int pos = (tk & ~31) + ((t5 >> 4) << 2) + (((t5 >> 2) & 3) << 3) + (t5 & 3);
          ushort4 v;
          v.x = f2h(acc[mt][nt][0]); v.y = f2h(acc[mt][nt][1]);
          v.z = f2h(acc[mt][nt][2]); v.w = f2h(acc[mt][nt][3]);
          *(ushort4*)&O2[(((size_t)b * Hsz + h) * Dsz + d) * Tsz + pos] = v;
        }
    }
  } else {
#pragma unroll
    for (int mt = 0; mt < MT; ++mt)
#pragma unroll
      for (int nt = 0; nt < 4; ++nt) {
        const int m = row0 + wrow + mt * 16 + quad * 4;
        const int n = col0 + wn * 64 + nt * 16 + l16;
        const float bv = bias[n];
#pragma unroll
        for (int r = 0; r < 4; ++r)
          Of[(size_t)(m + r) * Csz + n] = acc[mt][nt][r] + bv;
      }
  }
}

// ---------------------------------------------------------------------------
// MFMA flash attention v6: triangle pairing + 4-WAY KEY SPLIT for TLP.
// Block = 512 thr = 8 waves = (ww: tile pair) x (sp: key chunks c==sp mod 4).
// Plain-exp attention is LINEAR over key chunks -> partials (O, lsum) just
// add; combined in LDS at the end. Grid 512 = 2 blocks/CU = 16 waves/CU =
// 4 waves/SIMD (vs R7's 1/SIMD, occupancy 8.4%). Each sp-group has its own
// 16KB dbuf staged via global_load_lds; inner math identical to R7.
// ---------------------------------------------------------------------------
__global__ __launch_bounds__(512, 4) void attn_mfma(
    const unsigned short* __restrict__ Qb,   // bf16 [B,H,T,D], *QSCALE
    const unsigned short* __restrict__ Kb,   // bf16 [B,H,T,D]
    const unsigned short* __restrict__ VTb,  // f16  [B,H,D,T'] key-swizzled
    unsigned short* __restrict__ Y) {        // bf16 [B,T,C]
  __shared__ __align__(16) unsigned char SMEM[65536];  // 4 sp-groups x 16KB dbuf
  // group sp, buffer b: K at SMEM + sp*16384 + b*4096, V at +8192
#define KSP(spp, bb) ((unsigned short*)(SMEM + (spp) * 16384 + (bb) * 4096))
#define VSP(spp, bb) ((unsigned short*)(SMEM + (spp) * 16384 + 8192 + (bb) * 4096))

  const int tid = threadIdx.x;
  const int wave = tid >> 6, lane = tid & 63;
  const int quad = lane >> 4, l16 = lane & 15;
  const int ww = wave & 1;                 // tile-pair selector
  const int sp = wave >> 1;                // key split 0..3
  const int ltid = tid & 127;              // thread within sp-group

  const int bh = blockIdx.x & 31;          // head pinned to XCD (bh%8)
  const int jg = blockIdx.x >> 5;          // 0..15
  const int ja = 2 * jg + ww;              // light tile (0..31)
  const int jb = 63 - ja;                  // heavy tile (32..63)
  const int qa = ja << 5, qb = jb << 5;

  const unsigned short* Qh = Qb + (size_t)bh * Tsz * Dsz;
  const unsigned short* Kh = Kb + (size_t)bh * Tsz * Dsz;
  const unsigned short* Vh = VTb + (size_t)bh * Dsz * Tsz;

  // staging source addrs: 128 thr/group cover 4KB K + 4KB V per chunk,
  // 2x16B each. K element-chunk e: key=e>>3, kc=e&7 (xor-swizzled);
  // V element-chunk e: d=e>>2, vc=e&3.
  const int ke0 = ltid, ke1 = ltid + 128;
  const int kkey0 = ke0 >> 3, kc0 = ke0 & 7;
  const int kkey1 = ke1 >> 3, kc1 = ke1 & 7;
  const unsigned short* gK0 = Kh + (size_t)kkey0 * Dsz + ((kc0 ^ (kkey0 & 7)) << 3);
  const unsigned short* gK1 = Kh + (size_t)kkey1 * Dsz + ((kc1 ^ (kkey1 & 7)) << 3);
  const int vd0 = ltid >> 2, vc0 = ltid & 3;
  const int vd1 = vd0 + 32;
  const unsigned short* gV0 = Vh + (size_t)vd0 * Tsz + ((vc0 ^ ((vd0 + (vd0 >> 2)) & 3)) << 3);
  const unsigned short* gV1 = Vh + (size_t)vd1 * Tsz + ((vc0 ^ ((vd1 + (vd1 >> 2)) & 3)) << 3);
  // wave-uniform LDS dsts: wave ww covers chunks [ww*64,+64) and [128+ww*64,+64)
  const int wo = ww * 512;   // shorts

  // Q frags for both tiles: B-operand (col=q=l16, k=quad*8+jj over d)
  frag8 qfa[2][2], qfb[2][2];
#pragma unroll
  for (int m = 0; m < 2; ++m)
#pragma unroll
    for (int ks = 0; ks < 2; ++ks) {
      qfa[m][ks] = *(const frag8*)(Qh + (size_t)(qa + m * 16 + l16) * Dsz + ks * 32 + quad * 8);
      qfb[m][ks] = *(const frag8*)(Qh + (size_t)(qb + m * 16 + l16) * Dsz + ks * 32 + quad * 8);
    }

  f4 oa[2][4], ob[2][4];
  float lsa[2] = {0.f, 0.f}, lsb[2] = {0.f, 0.f};
#pragma unroll
  for (int m = 0; m < 2; ++m)
#pragma unroll
    for (int nt = 0; nt < 4; ++nt) {
      oa[m][nt] = (f4){0.f, 0.f, 0.f, 0.f};
      ob[m][nt] = (f4){0.f, 0.f, 0.f, 0.f};
    }
  const f4 zf = (f4){0.f, 0.f, 0.f, 0.f};
  const int fl = (l16 + (l16 >> 2)) & 3;   // V read swizzle key

  const int jbmax = 63 - 2 * jg;           // block's largest jb (ww=0)
  const int nch = (jbmax >> 2) + 1;        // uniform iteration count

  // prologue: stage group chunks sp (buf0) and sp+4 (buf1)
  {
    const size_t kof0 = (size_t)(sp << 5) * Dsz, kof1 = (size_t)((sp + 4) << 5) * Dsz;
    const int vof0 = sp << 5, vof1 = (sp + 4) << 5;
    GLDS16(gK0 + kof0, KSP(sp, 0) + wo);
    GLDS16(gK1 + kof0, KSP(sp, 0) + wo + 1024);
    GLDS16(gV0 + vof0, VSP(sp, 0) + wo);
    GLDS16(gV1 + vof0, VSP(sp, 0) + wo + 1024);
    GLDS16(gK0 + kof1, KSP(sp, 1) + wo);
    GLDS16(gK1 + kof1, KSP(sp, 1) + wo + 1024);
    GLDS16(gV0 + vof1, VSP(sp, 1) + wo);
    GLDS16(gV1 + vof1, VSP(sp, 1) + wo + 1024);
  }
  __syncthreads();

  for (int i = 0; i < nch; ++i) {
    const int c = sp + 4 * i;
    const int bsel = i & 1;
    if (c <= jb) {
      const unsigned short* Kl = KSP(sp, bsel);
      const unsigned short* Vl = VSP(sp, bsel);
      frag8 kf[2][2];
#pragma unroll
      for (int n = 0; n < 2; ++n)
#pragma unroll
        for (int ks = 0; ks < 2; ++ks)
          kf[n][ks] = *(const frag8*)&Kl[(n * 16 + l16) * 64 + (((ks * 4 + quad) ^ (l16 & 7)) << 3)];
      frag8h vf[4];
#pragma unroll
      for (int nt = 0; nt < 4; ++nt)
        vf[nt] = *(const frag8h*)&Vl[(nt * 16 + l16) * 32 + ((quad ^ fl) << 3)];

      // ---- tile B
      {
        f4 st[2][2];
#pragma unroll
        for (int n = 0; n < 2; ++n)
#pragma unroll
          for (int m = 0; m < 2; ++m) {
            f4 a = __builtin_amdgcn_mfma_f32_16x16x32_bf16(kf[n][0], qfb[m][0], zf, 0, 0, 0);
            st[n][m] = __builtin_amdgcn_mfma_f32_16x16x32_bf16(kf[n][1], qfb[m][1], a, 0, 0, 0);
          }
        const bool dm = (c == jb);
        frag4h paf[2][2];
#pragma unroll
        for (int m = 0; m < 2; ++m) {
          const int qq = m * 16 + l16;
#pragma unroll
          for (int n = 0; n < 2; ++n) {
            const int key0 = n * 16 + quad * 4;
            float p[4];
#pragma unroll
            for (int r = 0; r < 4; ++r) {
              float sv = st[n][m][r];
              if (dm && (key0 + r > qq)) sv = -INFINITY;
              p[r] = __builtin_amdgcn_exp2f(sv);
            }
            lsb[m] += (p[0] + p[1]) + (p[2] + p[3]);
            frag4h ph;
            ph[0] = (_Float16)p[0]; ph[1] = (_Float16)p[1];
            ph[2] = (_Float16)p[2]; ph[3] = (_Float16)p[3];
            paf[m][n] = ph;
          }
        }
#pragma unroll
        for (int m = 0; m < 2; ++m)
#pragma unroll
          for (int nt = 0; nt < 4; ++nt) {
            const frag4h vlo = __builtin_shufflevector(vf[nt], vf[nt], 0, 1, 2, 3);
            const frag4h vhi = __builtin_shufflevector(vf[nt], vf[nt], 4, 5, 6, 7);
            f4 a = __builtin_amdgcn_mfma_f32_16x16x16f16(paf[m][0], vlo, ob[m][nt], 0, 0, 0);
            ob[m][nt] = __builtin_amdgcn_mfma_f32_16x16x16f16(paf[m][1], vhi, a, 0, 0, 0);
          }
      }

      // ---- tile A
      if (c <= ja) {
        f4 st[2][2];
#pragma unroll
        for (int n = 0; n < 2; ++n)
#pragma unroll
          for (int m = 0; m < 2; ++m) {
            f4 a = __builtin_amdgcn_mfma_f32_16x16x32_bf16(kf[n][0], qfa[m][0], zf, 0, 0, 0);
            st[n][m] = __builtin_amdgcn_mfma_f32_16x16x32_bf16(kf[n][1], qfa[m][1], a, 0, 0, 0);
          }
        const bool dm = (c == ja);
        frag4h paf[2][2];
#pragma unroll
        for (int m = 0; m < 2; ++m) {
          const int qq = m * 16 + l16;
#pragma unroll
          for (int n = 0; n < 2; ++n) {
            const int key0 = n * 16 + quad * 4;
            float p[4];
#pragma unroll
            for (int r = 0; r < 4; ++r) {
              float sv = st[n][m][r];
              if (dm && (key0 + r > qq)) sv = -INFINITY;
              p[r] = __builtin_amdgcn_exp2f(sv);
            }
            lsa[m] += (p[0] + p[1]) + (p[2] + p[3]);
            frag4h ph;
            ph[0] = (_Float16)p[0]; ph[1] = (_Float16)p[1];
            ph[2] = (_Float16)p[2]; ph[3] = (_Float16)p[3];
            paf[m][n] = ph;
          }
        }
#pragma unroll
        for (int m = 0; m < 2; ++m)
#pragma unroll
          for (int nt = 0; nt < 4; ++nt) {
            const frag4h vlo = __builtin_shufflevector(vf[nt], vf[nt], 0, 1, 2, 3);
            const frag4h vhi = __builtin_shufflevector(vf[nt], vf[nt], 4, 5, 6, 7);
            f4 a = __builtin_amdgcn_mfma_f32_16x16x16f16(paf[m][0], vlo, oa[m][nt], 0, 0, 0);
            oa[m][nt] = __builtin_amdgcn_mfma_f32_16x16x16f16(paf[m][1], vhi, a, 0, 0, 0);
          }
      }
    }
    __syncthreads();
    if (i + 2 < nch) {
      const int c2 = sp + 4 * (i + 2);
      const size_t kof = (size_t)(c2 << 5) * Dsz;
      const int vof = c2 << 5;
      GLDS16(gK0 + kof, KSP(sp, bsel) + wo);
      GLDS16(gK1 + kof, KSP(sp, bsel) + wo + 1024);
      GLDS16(gV0 + vof, VSP(sp, bsel) + wo);
      GLDS16(gV1 + vof, VSP(sp, bsel) + wo + 1024);
    }
  }

  // ---- combine partials across sp (plain-exp linearity): LDS, 2 rounds.
  float* comb = (float*)SMEM;              // 6 slots x 64 lanes x 36 floats
  const int slot = (sp - 1) * 2 + ww;      // writers: sp=1..3
  float* cp = comb + (size_t)(slot * 64 + lane) * 36;

  // round 1: tile B
  if (sp != 0) {
#pragma unroll
    for (int m = 0; m < 2; ++m)
#pragma unroll
      for (int nt = 0; nt < 4; ++nt)
        *(f4*)(cp + m * 16 + nt * 4) = ob[m][nt];
    cp[32] = lsb[0]; cp[33] = lsb[1];
  }
  __syncthreads();
  if (sp == 0) {
#pragma unroll
    for (int s = 0; s < 3; ++s) {
      const float* rp = comb + (size_t)((s * 2 + ww) * 64 + lane) * 36;
#pragma unroll
      for (int m = 0; m < 2; ++m)
#pragma unroll
        for (int nt = 0; nt < 4; ++nt)
          ob[m][nt] += *(const f4*)(rp + m * 16 + nt * 4);
      lsb[0] += rp[32]; lsb[1] += rp[33];
    }
  }
  __syncthreads();
  // round 2: tile A
  if (sp != 0) {
#pragma unroll
    for (int m = 0; m < 2; ++m)
#pragma unroll
      for (int nt = 0; nt < 4; ++nt)
        *(f4*)(cp + m * 16 + nt * 4) = oa[m][nt];
    cp[32] = lsa[0]; cp[33] = lsa[1];
  }
  __syncthreads();
  if (sp == 0) {
#pragma unroll
    for (int s = 0; s < 3; ++s) {
      const float* rp = comb + (size_t)((s * 2 + ww) * 64 + lane) * 36;
#pragma unroll
      for (int m = 0; m < 2; ++m)
#pragma unroll
        for (int nt = 0; nt < 4; ++nt)
          oa[m][nt] += *(const f4*)(rp + m * 16 + nt * 4);
      lsa[0] += rp[32]; lsa[1] += rp[33];
    }

    // reduce per-q sums across quads, normalize, write out
#pragma unroll
    for (int m = 0; m < 2; ++m) {
      lsa[m] += __shfl_xor(lsa[m], 16);
      lsa[m] += __shfl_xor(lsa[m], 32);
      lsb[m] += __shfl_xor(lsb[m], 16);
      lsb[m] += __shfl_xor(lsb[m], 32);
    }
    const int b = bh >> 4, h = bh & 15;
#pragma unroll
    for (int m = 0; m < 2; ++m)
#pragma unroll
      for (int r = 0; r < 4; ++r) {
        const float inva = 1.f / __shfl(lsa[m], quad * 4 + r);
        const float invb = 1.f / __shfl(lsb[m], quad * 4 + r);
        const int ta = qa + m * 16 + quad * 4 + r;
        const int tb = qb + m * 16 + quad * 4 + r;
        unsigned short* ypa = Y + ((size_t)b * Tsz + ta) * Csz + h * 64 + l16;
        unsigned short* ypb = Y + ((size_t)b * Tsz + tb) * Csz + h * 64 + l16;
#pragma unroll
        for (int nt = 0; nt < 4; ++nt) {
          ypa[nt * 16] = f2bf(oa[m][nt][r] * inva);
          ypb[nt * 16] = f2bf(ob[m][nt][r] * invb);
        }
      }
  }
#undef KSP
#undef VSP
}

// ---------------------------------------------------------------------------
extern "C" void kernel_launch(void* const* d_in, const int* in_sizes, int n_in,
                              void* d_out, int out_size, void* d_ws, size_t ws_size,
                              hipStream_t stream) {
  const float* x  = (const float*)d_in[0];
  const float* Wq = (const float*)d_in[1];
  const float* Wk = (const float*)d_in[2];
  const float* Wv = (const float*)d_in[3];
  const float* Wo = (const float*)d_in[4];
  const float* bo = (const float*)d_in[5];

  const size_t NEL = (size_t)Bsz * Tsz * Csz;     // 4M
  const size_t WSZ = (size_t)Csz * Csz;           // 1M
  unsigned short* xb  = (unsigned short*)d_ws;    // 8 MB
  unsigned short* WT  = xb + NEL;                 // 6 MB (Wq|Wk|Wv ^T)
  unsigned short* WoT = WT + 3 * WSZ;             // 2 MB
  unsigned short* Qb  = WoT + WSZ;                // 8 MB
  unsigned short* Kb  = Qb + NEL;                 // 8 MB
  unsigned short* VTb = Kb + NEL;                 // 8 MB (f16 bits, key-swizzled)
  unsigned short* Yb  = VTb + NEL;                // 8 MB

  cast_x<<<NEL / 2048, 256, 0, stream>>>(x, xb);
  transpose_cast<<<1024, 256, 0, stream>>>(Wq, Wk, Wv, Wo,
                                           WT, WT + WSZ, WT + 2 * WSZ, WoT);

  // fused QKV: C[4096][3072] = xb . WT^T   (128x128 tiles)
  mm_bt<0, 4><<<dim3(24, 32), 256, 0, stream>>>(xb, WT, nullptr, Qb, Kb, VTb, nullptr);

  attn_mfma<<<512, 512, 0, stream>>>(Qb, Kb, VTb, Yb);

  // out: C[4096][1024] = Yb . WoT^T + b    (64x128 tiles -> 512 blocks)
  mm_bt<2, 2><<<dim3(8, 64), 256, 0, stream>>>(Yb, WoT, bo, nullptr, nullptr, nullptr,
                                               (float*)d_out);
}

// Round 9
// 180.862 us; speedup vs baseline: 1.4737x; 1.4737x over previous
//
#include <hip/hip_runtime.h>
#include <hip/hip_bf16.h>
#include <math.h>

#define Bsz 2
#define Tsz 2048
#define Csz 1024
#define Hsz 16
#define Dsz 64

typedef __attribute__((ext_vector_type(8))) short frag8;      // 8 bf16
typedef __attribute__((ext_vector_type(4))) float f4;         // MFMA C/D
typedef __attribute__((ext_vector_type(8))) unsigned short us8;
typedef __attribute__((ext_vector_type(4))) _Float16 frag4h;  // 4 f16
typedef __attribute__((ext_vector_type(8))) _Float16 frag8h;  // 8 f16

static __device__ __forceinline__ unsigned short f2bf(float f) {
  union { __hip_bfloat16 h; unsigned short u; } c;
  c.h = __float2bfloat16(f);
  return c.u;
}
static __device__ __forceinline__ unsigned short f2h(float f) {
  union { _Float16 h; unsigned short u; } c;
  c.h = (_Float16)f;
  return c.u;
}

#define GLDS16(g, l)                                                        \
  __builtin_amdgcn_global_load_lds(                                         \
      (const __attribute__((address_space(1))) void*)(g),                   \
      (__attribute__((address_space(3))) void*)(l), 16, 0, 0)

// Q pre-scale: 1/sqrt(64) * log2(e)  (exp2 in attention)
#define QSCALE 0.18033688f

// ---------------------------------------------------------------------------
// cast x fp32 -> bf16
// ---------------------------------------------------------------------------
__global__ __launch_bounds__(256) void cast_x(const float* __restrict__ x,
                                              unsigned short* __restrict__ xb) {
  const int i = (blockIdx.x * 256 + threadIdx.x) * 8;
  const float4 a = *(const float4*)(x + i);
  const float4 b = *(const float4*)(x + i + 4);
  us8 v;
  v[0] = f2bf(a.x); v[1] = f2bf(a.y); v[2] = f2bf(a.z); v[3] = f2bf(a.w);
  v[4] = f2bf(b.x); v[5] = f2bf(b.y); v[6] = f2bf(b.z); v[7] = f2bf(b.w);
  *(us8*)(xb + i) = v;
}

// ---------------------------------------------------------------------------
// Transpose-cast: 4x fp32 [1024][1024] -> bf16 transposed.
// ---------------------------------------------------------------------------
__global__ __launch_bounds__(256) void transpose_cast(
    const float* __restrict__ s0, const float* __restrict__ s1,
    const float* __restrict__ s2, const float* __restrict__ s3,
    unsigned short* __restrict__ d0, unsigned short* __restrict__ d1,
    unsigned short* __restrict__ d2, unsigned short* __restrict__ d3) {
  __shared__ float Ls[64][65];
  const int mat = blockIdx.x >> 8;
  const int tile = blockIdx.x & 255;
  const float* src = mat == 0 ? s0 : mat == 1 ? s1 : mat == 2 ? s2 : s3;
  unsigned short* dst = mat == 0 ? d0 : mat == 1 ? d1 : mat == 2 ? d2 : d3;
  const int tr0 = (tile >> 4) << 6, tc0 = (tile & 15) << 6;
  const int t = threadIdx.x;
  const int lr = t >> 4, lc = (t & 15) << 2;
#pragma unroll
  for (int j = 0; j < 4; ++j) {
    const float4 v = *(const float4*)(src + (size_t)(tr0 + lr + j * 16) * 1024 + tc0 + lc);
    Ls[lr + j * 16][lc + 0] = v.x;
    Ls[lr + j * 16][lc + 1] = v.y;
    Ls[lr + j * 16][lc + 2] = v.z;
    Ls[lr + j * 16][lc + 3] = v.w;
  }
  __syncthreads();
#pragma unroll
  for (int j = 0; j < 4; ++j) {
    ushort4 v;
    v.x = f2bf(Ls[lc + 0][lr + j * 16]);
    v.y = f2bf(Ls[lc + 1][lr + j * 16]);
    v.z = f2bf(Ls[lc + 2][lr + j * 16]);
    v.w = f2bf(Ls[lc + 3][lr + j * 16]);
    *(ushort4*)(dst + (size_t)(tc0 + lr + j * 16) * 1024 + tr0 + lc) = v;
  }
}

// ---------------------------------------------------------------------------
// bf16 MFMA GEMM: C[M][N] = A[M][K=1024] . Bt[N][K]^T.  BK=64, 128-col tile.
// MODE 0 (MT=4): fused QKV (N=3072): col<1024 -> Qb (*QSCALE) bf16 [B,H,T,D];
//     col<2048 -> Kb bf16 [B,H,T,D]; else -> VTb f16 [B,H,D,T'] key-swizzled.
// MODE 2 (MT=2): OUT: fp32 + bias, [M][1024]
// ---------------------------------------------------------------------------
template <int MODE, int MT>
__global__ __launch_bounds__(256) void mm_bt(
    const unsigned short* __restrict__ A, const unsigned short* __restrict__ Bt,
    const float* __restrict__ bias, unsigned short* __restrict__ O0,
    unsigned short* __restrict__ O1, unsigned short* __restrict__ O2,
    float* __restrict__ Of) {
  __shared__ __align__(16) unsigned short As[MT * 32 * 64];
  __shared__ __align__(16) unsigned short Bs[128 * 64];
  const int K = 1024;
  const int tid = threadIdx.x;
  const int wave = tid >> 6, lane = tid & 63;
  const int quad = lane >> 4, l16 = lane & 15;
  const int wrow = (wave >> 1) * (MT * 16), wn = wave & 1;
  const int row0 = blockIdx.y * (MT * 32), col0 = blockIdx.x << 7;

  const int sr = lane >> 3, sg = lane & 7;
  const int g0 = sg ^ sr;
  const unsigned short* gA = A + (size_t)(row0 + wave * (MT * 8) + sr) * K + (g0 << 3);
  const unsigned short* gB = Bt + (size_t)(col0 + wave * 32 + sr) * K + (g0 << 3);

  f4 acc[MT][4];
#pragma unroll
  for (int i = 0; i < MT; ++i)
#pragma unroll
    for (int j = 0; j < 4; ++j) acc[i][j] = (f4){0.f, 0.f, 0.f, 0.f};

  for (int kk = 0; kk < K; kk += 64) {
    __syncthreads();
#pragma unroll
    for (int s = 0; s < MT; ++s)
      GLDS16(gA + kk + (size_t)(s * 8) * K, &As[(wave * (MT * 8) + s * 8) * 64]);
#pragma unroll
    for (int s = 0; s < 4; ++s)
      GLDS16(gB + kk + (size_t)(s * 8) * K, &Bs[(wave * 32 + s * 8) * 64]);
    __syncthreads();

#pragma unroll
    for (int ks = 0; ks < 2; ++ks) {
      frag8 af[MT], bf[4];
#pragma unroll
      for (int mt = 0; mt < MT; ++mt) {
        const int r = wrow + mt * 16 + l16;
        af[mt] = *(const frag8*)&As[r * 64 + (((ks * 4 + quad) ^ (l16 & 7)) << 3)];
      }
#pragma unroll
      for (int nt = 0; nt < 4; ++nt) {
        const int n = wn * 64 + nt * 16 + l16;
        bf[nt] = *(const frag8*)&Bs[n * 64 + (((ks * 4 + quad) ^ (l16 & 7)) << 3)];
      }
#pragma unroll
      for (int mt = 0; mt < MT; ++mt)
#pragma unroll
        for (int nt = 0; nt < 4; ++nt)
          acc[mt][nt] = __builtin_amdgcn_mfma_f32_16x16x32_bf16(af[mt], bf[nt], acc[mt][nt], 0, 0, 0);
    }
  }

  // ---- epilogue. C/D: col = l16, row = quad*4 + reg.
  if (MODE == 0) {
    if (col0 < 2048) {
      const bool isK = (col0 >= 1024);
      unsigned short* dst = isK ? O1 : O0;
      const float sc = isK ? 1.0f : QSCALE;
#pragma unroll
      for (int mt = 0; mt < MT; ++mt)
#pragma unroll
        for (int nt = 0; nt < 4; ++nt) {
          const int m = row0 + wrow + mt * 16 + quad * 4;          // token
          const int n = (col0 & 1023) + wn * 64 + nt * 16 + l16;   // channel
          const int b = m >> 11, h = n >> 6, d = n & 63;
#pragma unroll
          for (int r = 0; r < 4; ++r) {
            const int tk = (m + r) & (Tsz - 1);
            dst[(((size_t)b * Hsz + h) * Tsz + tk) * Dsz + d] = f2bf(acc[mt][nt][r] * sc);
          }
        }
    } else {
      // V^T f16 [B,H,D,T'] key-swizzled; 4 consecutive tokens packed
#pragma unroll
      for (int mt = 0; mt < MT; ++mt)
#pragma unroll
        for (int nt = 0; nt < 4; ++nt) {
          const int tok = row0 + wrow + mt * 16 + quad * 4;
          const int ch = (col0 - 2048) + wn * 64 + nt * 16 + l16;
          const int b = tok >> 11, tk = tok & (Tsz - 1);
          const int h = ch >> 6, d = ch & 63;
          const int t5 = tk & 31;
          const int pos = (tk & ~31) + ((t5 >> 4) << 2) + (((t5 >> 2) & 3) << 3) + (t5 & 3);
          ushort4 v;
          v.x = f2h(acc[mt][nt][0]); v.y = f2h(acc[mt][nt][1]);
          v.z = f2h(acc[mt][nt][2]); v.w = f2h(acc[mt][nt][3]);
          *(ushort4*)&O2[(((size_t)b * Hsz + h) * Dsz + d) * Tsz + pos] = v;
        }
    }
  } else {
#pragma unroll
    for (int mt = 0; mt < MT; ++mt)
#pragma unroll
      for (int nt = 0; nt < 4; ++nt) {
        const int m = row0 + wrow + mt * 16 + quad * 4;
        const int n = col0 + wn * 64 + nt * 16 + l16;
        const float bv = bias[n];
#pragma unroll
        for (int r = 0; r < 4; ++r)
          Of[(size_t)(m + r) * Csz + n] = acc[mt][nt][r] + bv;
      }
  }
}

// ---------------------------------------------------------------------------
// MFMA flash attention v7: ONE TILE PER WAVE x 4-way key split (no spill).
// Block = 512 thr = 8 waves = (t: tile ja|jb) x (sp: chunks c==sp mod 4).
// Pair (ja=pr, jb=63-pr) per block -> grid 32bh x 32pr = 1024 blocks,
// 2 resident/CU (64KB LDS) = 16 waves/CU = 4/SIMD. Per-wave state ~100 VGPR
// <= 128 cap (R8 held both tiles -> 150 -> scratch spill, 320MB writes).
// Plain-exp linearity: partials (O, lsum) just add; combined once in LDS.
// ---------------------------------------------------------------------------
__global__ __launch_bounds__(512, 4) void attn_mfma(
    const unsigned short* __restrict__ Qb,   // bf16 [B,H,T,D], *QSCALE
    const unsigned short* __restrict__ Kb,   // bf16 [B,H,T,D]
    const unsigned short* __restrict__ VTb,  // f16  [B,H,D,T'] key-swizzled
    unsigned short* __restrict__ Y) {        // bf16 [B,T,C]
  __shared__ __align__(16) unsigned char SMEM[65536];  // 4 sp-groups x 16KB dbuf
#define KSP(spp, bb) ((unsigned short*)(SMEM + (spp) * 16384 + (bb) * 4096))
#define VSP(spp, bb) ((unsigned short*)(SMEM + (spp) * 16384 + 8192 + (bb) * 4096))

  const int tid = threadIdx.x;
  const int wave = tid >> 6, lane = tid & 63;
  const int quad = lane >> 4, l16 = lane & 15;
  const int t = wave & 1;                  // 0 -> tile ja, 1 -> tile jb
  const int sp = wave >> 1;                // key split 0..3
  const int ltid = tid & 127;              // thread within sp-group

  const int bh = blockIdx.x & 31;          // head pinned to XCD (bh%8)
  const int pr = blockIdx.x >> 5;          // 0..31, heavy pairs first
  const int ja = pr, jb = 63 - pr;
  const int j = t ? jb : ja;               // this wave's tile
  const int qb0 = j << 5;

  const unsigned short* Qh = Qb + (size_t)bh * Tsz * Dsz;
  const unsigned short* Kh = Kb + (size_t)bh * Tsz * Dsz;
  const unsigned short* Vh = VTb + (size_t)bh * Dsz * Tsz;

  // staging source addrs: 128 thr/group cover 4KB K + 4KB V per chunk,
  // 2x16B each (identical to R8, verified).
  const int ke0 = ltid, ke1 = ltid + 128;
  const int kkey0 = ke0 >> 3, kc0 = ke0 & 7;
  const int kkey1 = ke1 >> 3, kc1 = ke1 & 7;
  const unsigned short* gK0 = Kh + (size_t)kkey0 * Dsz + ((kc0 ^ (kkey0 & 7)) << 3);
  const unsigned short* gK1 = Kh + (size_t)kkey1 * Dsz + ((kc1 ^ (kkey1 & 7)) << 3);
  const int vd0 = ltid >> 2, vc0 = ltid & 3;
  const int vd1 = vd0 + 32;
  const unsigned short* gV0 = Vh + (size_t)vd0 * Tsz + ((vc0 ^ ((vd0 + (vd0 >> 2)) & 3)) << 3);
  const unsigned short* gV1 = Vh + (size_t)vd1 * Tsz + ((vc0 ^ ((vd1 + (vd1 >> 2)) & 3)) << 3);
  const int wo = t * 512;                  // this wave's staging half (shorts)

  // Q frags (this tile only): B-operand (col=q=l16, k=quad*8+jj over d)
  frag8 qf[2][2];
#pragma unroll
  for (int m = 0; m < 2; ++m)
#pragma unroll
    for (int ks = 0; ks < 2; ++ks)
      qf[m][ks] = *(const frag8*)(Qh + (size_t)(qb0 + m * 16 + l16) * Dsz + ks * 32 + quad * 8);

  f4 o[2][4];
  float lsum[2] = {0.f, 0.f};
#pragma unroll
  for (int m = 0; m < 2; ++m)
#pragma unroll
    for (int nt = 0; nt < 4; ++nt) o[m][nt] = (f4){0.f, 0.f, 0.f, 0.f};
  const f4 zf = (f4){0.f, 0.f, 0.f, 0.f};
  const int fl = (l16 + (l16 >> 2)) & 3;   // V read swizzle key

  const int nch = (jb >> 2) + 1;           // uniform iterations (sp=0 of jb)

  // prologue: stage group chunks sp (buf0) and sp+4 (buf1)
  {
    const size_t kof0 = (size_t)(sp << 5) * Dsz, kof1 = (size_t)((sp + 4) << 5) * Dsz;
    const int vof0 = sp << 5, vof1 = (sp + 4) << 5;
    GLDS16(gK0 + kof0, KSP(sp, 0) + wo);
    GLDS16(gK1 + kof0, KSP(sp, 0) + wo + 1024);
    GLDS16(gV0 + vof0, VSP(sp, 0) + wo);
    GLDS16(gV1 + vof0, VSP(sp, 0) + wo + 1024);
    GLDS16(gK0 + kof1, KSP(sp, 1) + wo);
    GLDS16(gK1 + kof1, KSP(sp, 1) + wo + 1024);
    GLDS16(gV0 + vof1, VSP(sp, 1) + wo);
    GLDS16(gV1 + vof1, VSP(sp, 1) + wo + 1024);
  }
  __syncthreads();

  for (int i = 0; i < nch; ++i) {
    const int c = sp + 4 * i;
    const int bsel = i & 1;
    if (c <= j) {
      const unsigned short* Kl = KSP(sp, bsel);
      const unsigned short* Vl = VSP(sp, bsel);
      frag8 kf[2][2];
#pragma unroll
      for (int n = 0; n < 2; ++n)
#pragma unroll
        for (int ks = 0; ks < 2; ++ks)
          kf[n][ks] = *(const frag8*)&Kl[(n * 16 + l16) * 64 + (((ks * 4 + quad) ^ (l16 & 7)) << 3)];
      frag8h vf[4];
#pragma unroll
      for (int nt = 0; nt < 4; ++nt)
        vf[nt] = *(const frag8h*)&Vl[(nt * 16 + l16) * 32 + ((quad ^ fl) << 3)];

      f4 st[2][2];
#pragma unroll
      for (int n = 0; n < 2; ++n)
#pragma unroll
        for (int m = 0; m < 2; ++m) {
          f4 a = __builtin_amdgcn_mfma_f32_16x16x32_bf16(kf[n][0], qf[m][0], zf, 0, 0, 0);
          st[n][m] = __builtin_amdgcn_mfma_f32_16x16x32_bf16(kf[n][1], qf[m][1], a, 0, 0, 0);
        }
      const bool dm = (c == j);
      frag4h paf[2][2];
#pragma unroll
      for (int m = 0; m < 2; ++m) {
        const int qq = m * 16 + l16;
#pragma unroll
        for (int n = 0; n < 2; ++n) {
          const int key0 = n * 16 + quad * 4;
          float p[4];
#pragma unroll
          for (int r = 0; r < 4; ++r) {
            float sv = st[n][m][r];
            if (dm && (key0 + r > qq)) sv = -INFINITY;
            p[r] = __builtin_amdgcn_exp2f(sv);
          }
          lsum[m] += (p[0] + p[1]) + (p[2] + p[3]);
          frag4h ph;
          ph[0] = (_Float16)p[0]; ph[1] = (_Float16)p[1];
          ph[2] = (_Float16)p[2]; ph[3] = (_Float16)p[3];
          paf[m][n] = ph;
        }
      }
#pragma unroll
      for (int m = 0; m < 2; ++m)
#pragma unroll
        for (int nt = 0; nt < 4; ++nt) {
          const frag4h vlo = __builtin_shufflevector(vf[nt], vf[nt], 0, 1, 2, 3);
          const frag4h vhi = __builtin_shufflevector(vf[nt], vf[nt], 4, 5, 6, 7);
          f4 a = __builtin_amdgcn_mfma_f32_16x16x16f16(paf[m][0], vlo, o[m][nt], 0, 0, 0);
          o[m][nt] = __builtin_amdgcn_mfma_f32_16x16x16f16(paf[m][1], vhi, a, 0, 0, 0);
        }
    }
    __syncthreads();
    if (i + 2 < nch) {
      const int c2 = sp + 4 * (i + 2);
      const size_t kof = (size_t)(c2 << 5) * Dsz;
      const int vof = c2 << 5;
      GLDS16(gK0 + kof, KSP(sp, bsel) + wo);
      GLDS16(gK1 + kof, KSP(sp, bsel) + wo + 1024);
      GLDS16(gV0 + vof, VSP(sp, bsel) + wo);
      GLDS16(gV1 + vof, VSP(sp, bsel) + wo + 1024);
    }
  }

  // ---- combine partials across sp (plain-exp linearity), one LDS round.
  // 6 writer waves (sp=1..3, both t), stride 37 floats (gcd(37*?,32) walk ->
  // <=2-way conflicts on b128).
  float* comb = (float*)SMEM;
  const int slot = (sp - 1) * 2 + t;       // 0..5 for sp>=1
  float* cp = comb + (size_t)(slot * 64 + lane) * 37;
  if (sp != 0) {
#pragma unroll
    for (int m = 0; m < 2; ++m)
#pragma unroll
      for (int nt = 0; nt < 4; ++nt)
        *(f4*)(cp + m * 16 + nt * 4) = o[m][nt];
    cp[32] = lsum[0]; cp[33] = lsum[1];
  }
  __syncthreads();
  if (sp == 0) {
#pragma unroll
    for (int s = 0; s < 3; ++s) {
      const float* rp = comb + (size_t)((s * 2 + t) * 64 + lane) * 37;
#pragma unroll
      for (int m = 0; m < 2; ++m)
#pragma unroll
        for (int nt = 0; nt < 4; ++nt)
          o[m][nt] += *(const f4*)(rp + m * 16 + nt * 4);
      lsum[0] += rp[32]; lsum[1] += rp[33];
    }

    // reduce per-q sums across quads, normalize, write out
#pragma unroll
    for (int m = 0; m < 2; ++m) {
      lsum[m] += __shfl_xor(lsum[m], 16);
      lsum[m] += __shfl_xor(lsum[m], 32);
    }
    const int b = bh >> 4, h = bh & 15;
#pragma unroll
    for (int m = 0; m < 2; ++m)
#pragma unroll
      for (int r = 0; r < 4; ++r) {
        const float inv = 1.f / __shfl(lsum[m], quad * 4 + r);
        const int tk = qb0 + m * 16 + quad * 4 + r;
        unsigned short* yp = Y + ((size_t)b * Tsz + tk) * Csz + h * 64 + l16;
#pragma unroll
        for (int nt = 0; nt < 4; ++nt)
          yp[nt * 16] = f2bf(o[m][nt][r] * inv);
      }
  }
#undef KSP
#undef VSP
}

// ---------------------------------------------------------------------------
extern "C" void kernel_launch(void* const* d_in, const int* in_sizes, int n_in,
                              void* d_out, int out_size, void* d_ws, size_t ws_size,
                              hipStream_t stream) {
  const float* x  = (const float*)d_in[0];
  const float* Wq = (const float*)d_in[1];
  const float* Wk = (const float*)d_in[2];
  const float* Wv = (const float*)d_in[3];
  const float* Wo = (const float*)d_in[4];
  const float* bo = (const float*)d_in[5];

  const size_t NEL = (size_t)Bsz * Tsz * Csz;     // 4M
  const size_t WSZ = (size_t)Csz * Csz;           // 1M
  unsigned short* xb  = (unsigned short*)d_ws;    // 8 MB
  unsigned short* WT  = xb + NEL;                 // 6 MB (Wq|Wk|Wv ^T)
  unsigned short* WoT = WT + 3 * WSZ;             // 2 MB
  unsigned short* Qb  = WoT + WSZ;                // 8 MB
  unsigned short* Kb  = Qb + NEL;                 // 8 MB
  unsigned short* VTb = Kb + NEL;                 // 8 MB (f16 bits, key-swizzled)
  unsigned short* Yb  = VTb + NEL;                // 8 MB

  cast_x<<<NEL / 2048, 256, 0, stream>>>(x, xb);
  transpose_cast<<<1024, 256, 0, stream>>>(Wq, Wk, Wv, Wo,
                                           WT, WT + WSZ, WT + 2 * WSZ, WoT);

  // fused QKV: C[4096][3072] = xb . WT^T   (128x128 tiles)
  mm_bt<0, 4><<<dim3(24, 32), 256, 0, stream>>>(xb, WT, nullptr, Qb, Kb, VTb, nullptr);

  attn_mfma<<<1024, 512, 0, stream>>>(Qb, Kb, VTb, Yb);

  // out: C[4096][1024] = Yb . WoT^T + b    (64x128 tiles -> 512 blocks)
  mm_bt<2, 2><<<dim3(8, 64), 256, 0, stream>>>(Yb, WoT, bo, nullptr, nullptr, nullptr,
                                               (float*)d_out);
}